// Round 12
// baseline (172.664 us; speedup 1.0000x reference)
//
#include <hip/hip_runtime.h>
#include <hip/hip_bf16.h>
#include <math.h>

// Problem constants: B=8192, E=16, H=1024
#define B_SZ 8192
#define H_SZ 1024
#define E_SZ 16
#define SIM_THR_I 12903   // 0.8 * 127 * 127 = 12903.2 -> D > 12903
typedef float floatx4 __attribute__((ext_vector_type(4)));
typedef int   intx4   __attribute__((ext_vector_type(4)));

// ---------------- workspace layout ----------------
// 0: float gsum | 4: uint gcnt | 8: uint done
#define OFF_NE   4096
#define OFF_L    65536
#define OFF_P    (65536 + 524288)
#define OFF_EMB  2097152   // i8 emb, MFMA-native layout: 8 MB

// MFMA-native i8 layout (for mfma_i32_16x16x64_i8, lane q*16+m holds rows m,
// k in [q*16, q*16+16) contiguous):
// addr(r,k) = (r>>4)*16384 + (k>>6)*1024 + ((k>>4)&3)*256 + (r&15)*16 + (k&15)
// => one global_load_dwordx4 per fragment at group*16384 + kt*1024 + lane*16.

__device__ __forceinline__ unsigned int pack4_i8(float4 v, float s) {
    int a = (int)rintf(v.x * s), b = (int)rintf(v.y * s);
    int c = (int)rintf(v.z * s), d = (int)rintf(v.w * s);
    return (a & 255) | ((b & 255) << 8) | ((c & 255) << 16) | ((d & 255) << 24);
}

// ---------------------------------------------------------------------------
// Prep: blocks 0..511 normalize 16 rows each -> i8 MFMA-native layout with
// LDS-staged coalesced writes; blocks 512..543 softmax tables + accum init.
// ---------------------------------------------------------------------------
__global__ __launch_bounds__(256)
void prep_kernel(const float* __restrict__ rp,
                 const float* __restrict__ emb,
                 unsigned char* __restrict__ out8,
                 float* __restrict__ L, float* __restrict__ P,
                 float* __restrict__ ne,
                 float* __restrict__ gsum, unsigned int* __restrict__ gcnt,
                 unsigned int* __restrict__ done) {
    const int b = blockIdx.x;
    const int tid = threadIdx.x;
    if (b < 512) {
        __shared__ __align__(16) unsigned char stage[16 * 1040]; // padded rows
        const int wave = tid >> 6, lane = tid & 63;
        const int g = b;
#pragma unroll
        for (int t = 0; t < 4; t++) {
            int r = g * 16 + wave * 4 + t;
            const float4* row4 = (const float4*)(emb + (size_t)r * H_SZ);
            float4 v0 = row4[lane * 4 + 0], v1 = row4[lane * 4 + 1];
            float4 v2 = row4[lane * 4 + 2], v3 = row4[lane * 4 + 3];
            float ss = v0.x*v0.x + v0.y*v0.y + v0.z*v0.z + v0.w*v0.w
                     + v1.x*v1.x + v1.y*v1.y + v1.z*v1.z + v1.w*v1.w
                     + v2.x*v2.x + v2.y*v2.y + v2.z*v2.z + v2.w*v2.w
                     + v3.x*v3.x + v3.y*v3.y + v3.z*v3.z + v3.w*v3.w;
#pragma unroll
            for (int off = 32; off > 0; off >>= 1) ss += __shfl_down(ss, off, 64);
            ss = __shfl(ss, 0, 64);
            float s = rsqrtf(ss) * 127.0f;
            uint4 c;
            c.x = pack4_i8(v0, s);
            c.y = pack4_i8(v1, s);
            c.z = pack4_i8(v2, s);
            c.w = pack4_i8(v3, s);
            *(uint4*)(stage + (r & 15) * 1040 + lane * 16) = c;
        }
        __syncthreads();
        // coalesced write-out: dst chunk d -> row m = d&15, src chunk
        // c = (d>>6)*4 + ((d>>4)&3)
#pragma unroll
        for (int p = 0; p < 4; p++) {
            int d = p * 256 + tid;
            int m = d & 15;
            int c = (d >> 6) * 4 + ((d >> 4) & 3);
            uint4 v = *(const uint4*)(stage + m * 1040 + c * 16);
            *(uint4*)(out8 + (size_t)g * 16384 + (size_t)d * 16) = v;
        }
    } else {
        int i = (b - 512) * 256 + tid;
        if (i == 0) { *gsum = 0.f; *gcnt = 0u; *done = 0u; }
        if (i >= B_SZ) return;
        const float* x = rp + i * E_SZ;
        float v[E_SZ];
        float m = -INFINITY;
#pragma unroll
        for (int k = 0; k < E_SZ; k++) { v[k] = x[k]; m = fmaxf(m, v[k]); }
        float s = 0.f;
#pragma unroll
        for (int k = 0; k < E_SZ; k++) s += expf(v[k] - m);
        float lse = m + logf(s);
        float nent = 0.f;
#pragma unroll
        for (int k = 0; k < E_SZ; k++) {
            float l = v[k] - lse;
            float p = expf(l);
            L[i * E_SZ + k] = l;
            P[i * E_SZ + k] = p;
            nent += p * l;
        }
        ne[i] = nent;
    }
}

// ---------------------------------------------------------------------------
// Main: 256x256 i8 MFMA sim tiles (1024 threads / 16 waves, each a 64x64
// quadrant). BARRIER-FREE K-loop: fragments loaded directly from global
// (L2/L1-resident, MFMA-native layout) into a 3-deep register pipeline —
// no LDS staging, no DMA port, no ds_read, no __syncthreads until epilogue.
// Waves in the same row-group read identical A bytes -> L1 broadcasts.
// 528 tiles = 66/XCD (owner-computes classes {x, x+8, 23-x, 31-x}).
// Epilogue: per-wave compaction into LDS lists; fused finalize.
// ---------------------------------------------------------------------------
__global__ __launch_bounds__(1024, 2)
void sim_kl_kernel(const unsigned char* __restrict__ embL,
                   const float* __restrict__ Lm, const float* __restrict__ Pm,
                   const float* __restrict__ ne,
                   float* __restrict__ gsum, unsigned int* __restrict__ gcnt,
                   unsigned int* __restrict__ done, float* __restrict__ out) {
    __shared__ unsigned short list[16][2048];   // 64 KB, epilogue only
    __shared__ float redf[16];
    __shared__ unsigned int redc[16];

    // --- blockIdx -> (bi, bj): XCD x owns bj panels {x, x+8, 23-x, 31-x} ---
    const int x = blockIdx.x & 7;
    int s = blockIdx.x >> 3;            // 0..65
    int bjs[4] = { x, x + 8, 23 - x, 31 - x };
    int bi = 0, bj = 0;
#pragma unroll
    for (int t = 0; t < 4; t++) {
        int n = bjs[t] + 1;             // tiles with bi <= bj
        if (s < n) { bj = bjs[t]; bi = s; break; }
        s -= n;
    }
    const int rowI = bi * 256, rowJ = bj * 256;

    const int tid  = threadIdx.x;
    const int lane = tid & 63;
    const int wave = tid >> 6;
    const int wrg = wave >> 2;          // A row quadrant 0..3 (x64 rows)
    const int wcg = wave & 3;           // B col quadrant 0..3 (x64 cols)
    const int quad = lane >> 4;
    const int l16  = lane & 15;

    intx4 acc[4][4];
#pragma unroll
    for (int mi = 0; mi < 4; mi++)
#pragma unroll
        for (int ni = 0; ni < 4; ni++) {
            intx4 z = {0, 0, 0, 0};
            acc[mi][ni] = z;
        }

    // fragment base pointers: one b128 per fragment per round
    const char* pA = (const char*)embL + (size_t)(bi * 16 + wrg * 4) * 16384 + lane * 16;
    const char* pB = (const char*)embL + (size_t)(bj * 16 + wcg * 4) * 16384 + lane * 16;

    // 3-deep register pipeline: rounds kt use buffer kt%3; prefetch kt+3
    intx4 fa[3][4], fb[3][4];
#pragma unroll
    for (int p = 0; p < 3; p++) {
#pragma unroll
        for (int mi = 0; mi < 4; mi++) {
            fa[p][mi] = *(const intx4*)(pA + mi * 16384 + p * 1024);
            fb[p][mi] = *(const intx4*)(pB + mi * 16384 + p * 1024);
        }
    }

#pragma unroll
    for (int kt = 0; kt < 16; kt++) {
        const int buf = kt % 3;
#pragma unroll
        for (int mi = 0; mi < 4; mi++)
#pragma unroll
            for (int ni = 0; ni < 4; ni++)
                acc[mi][ni] = __builtin_amdgcn_mfma_i32_16x16x64_i8(
                    fa[buf][mi], fb[buf][ni], acc[mi][ni], 0, 0, 0);
        if (kt + 3 < 16) {   // refill this buffer with round kt+3
            const int ko = (kt + 3) * 1024;
#pragma unroll
            for (int mi = 0; mi < 4; mi++) {
                fa[buf][mi] = *(const intx4*)(pA + mi * 16384 + ko);
                fb[buf][mi] = *(const intx4*)(pB + mi * 16384 + ko);
            }
        }
    }

    // ============== per-wave compaction epilogue (strict j>i) ===============
    unsigned short* wl = list[wave];
    int base = 0;
    // C/D layout (16x16 shape): col = lane&15, row = quad*4 + reg
#pragma unroll
    for (int mi = 0; mi < 4; mi++) {
#pragma unroll
        for (int ni = 0; ni < 4; ni++) {
#pragma unroll
            for (int r = 0; r < 4; r++) {
                int il = wrg * 64 + mi * 16 + quad * 4 + r;  // 0..255
                int jl = wcg * 64 + ni * 16 + l16;           // 0..255
                bool msk = (acc[mi][ni][r] > SIM_THR_I) && (rowJ + jl > rowI + il);
                unsigned long long bal = __ballot(msk);
                if (msk) {
                    int pos = base + __popcll(bal & ((1ull << lane) - 1ull));
                    if (pos < 2048) wl[pos] = (unsigned short)((il << 8) | jl);
                }
                base += __popcll(bal);
            }
        }
    }
    if (base > 2048) base = 2048;   // safety clamp (expected ~32/wave)

    float fsum = 0.f;
    unsigned int lcnt = 0;
    for (int t = lane; t < base; t += 64) {
        int e = wl[t];
        int i = rowI + (e >> 8), j = rowJ + (e & 255);
        const float4* Li4 = (const float4*)(Lm + i * E_SZ);
        const float4* Pj4 = (const float4*)(Pm + j * E_SZ);
        const float4* Lj4 = (const float4*)(Lm + j * E_SZ);
        const float4* Pi4 = (const float4*)(Pm + i * E_SZ);
        float d = 0.f, d2 = 0.f;
#pragma unroll
        for (int q = 0; q < 4; q++) {
            float4 a = Li4[q], bb = Pj4[q];
            d += a.x * bb.x + a.y * bb.y + a.z * bb.z + a.w * bb.w;
            float4 a2 = Lj4[q], b2 = Pi4[q];
            d2 += a2.x * b2.x + a2.y * b2.y + a2.z * b2.z + a2.w * b2.w;
        }
        fsum += (ne[j] - d) + (ne[i] - d2);
        lcnt += 2;
    }

#pragma unroll
    for (int off = 32; off > 0; off >>= 1) {
        fsum += __shfl_down(fsum, off, 64);
        lcnt += __shfl_down(lcnt, off, 64);
    }
    if (lane == 0) { redf[wave] = fsum; redc[wave] = lcnt; }
    __syncthreads();
    if (tid == 0) {
        float sv = 0.f;
        unsigned int c = 0u;
#pragma unroll
        for (int w = 0; w < 16; w++) { sv += redf[w]; c += redc[w]; }
        if (c > 0u) {
            atomicAdd(gsum, sv);
            atomicAdd(gcnt, c);
        }
        __threadfence();                       // make accumulators visible
        unsigned int old = atomicAdd(done, 1u);
        if (old == gridDim.x - 1) {            // last block finalizes
            float S = atomicAdd(gsum, 0.0f);   // device-scope atomic read
            unsigned int C = atomicAdd(gcnt, 0u);
            out[0] = (C > 0u) ? (S / (float)C) : 0.f;   // WEIGHT = 1.0
        }
    }
}

// ---------------------------------------------------------------------------
extern "C" void kernel_launch(void* const* d_in, const int* in_sizes, int n_in,
                              void* d_out, int out_size, void* d_ws, size_t ws_size,
                              hipStream_t stream) {
    const float* rp  = (const float*)d_in[0];
    const float* emb = (const float*)d_in[1];
    float* out = (float*)d_out;

    char* ws = (char*)d_ws;
    float*         gsum = (float*)(ws + 0);
    unsigned int*  gcnt = (unsigned int*)(ws + 4);
    unsigned int*  done = (unsigned int*)(ws + 8);
    float*         ne   = (float*)(ws + OFF_NE);
    float*         Lm   = (float*)(ws + OFF_L);
    float*         Pm   = (float*)(ws + OFF_P);
    unsigned char* embL = (unsigned char*)(ws + OFF_EMB);

    prep_kernel<<<512 + 32, 256, 0, stream>>>(rp, emb, embL, Lm, Pm, ne, gsum, gcnt, done);
    sim_kl_kernel<<<528, 1024, 0, stream>>>(embL, Lm, Pm, ne, gsum, gcnt, done, out);
}

// Round 13
// 144.148 us; speedup vs baseline: 1.1978x; 1.1978x over previous
//
#include <hip/hip_runtime.h>
#include <hip/hip_bf16.h>
#include <math.h>

// Problem constants: B=8192, E=16, H=1024
#define B_SZ 8192
#define H_SZ 1024
#define E_SZ 16
#define SIM_THR_I 12903   // 0.8 * 127 * 127 = 12903.2 -> D > 12903
typedef float floatx4 __attribute__((ext_vector_type(4)));
typedef int   intx4   __attribute__((ext_vector_type(4)));

// ---------------- workspace layout ----------------
// 0: float gsum | 4: uint gcnt | 8: uint done
#define OFF_NE   4096
#define OFF_L    65536
#define OFF_P    (65536 + 524288)
#define OFF_EMB  2097152   // i8 emb, MFMA-native layout: 8 MB

// MFMA-native i8 layout (for mfma_i32_16x16x64_i8, lane q*16+m holds rows m,
// k in [q*16, q*16+16) contiguous):
// addr(r,k) = (r>>4)*16384 + (k>>6)*1024 + ((k>>4)&3)*256 + (r&15)*16 + (k&15)

__device__ __forceinline__ void gload16(const void* g, void* l) {
    __builtin_amdgcn_global_load_lds(
        (const __attribute__((address_space(1))) void*)g,
        (__attribute__((address_space(3))) void*)l, 16, 0, 0);
}

__device__ __forceinline__ unsigned int pack4_i8(float4 v, float s) {
    int a = (int)rintf(v.x * s), b = (int)rintf(v.y * s);
    int c = (int)rintf(v.z * s), d = (int)rintf(v.w * s);
    return (a & 255) | ((b & 255) << 8) | ((c & 255) << 16) | ((d & 255) << 24);
}

// ---------------------------------------------------------------------------
// Prep: blocks 0..511 normalize 16 rows each -> i8 MFMA-native layout with
// LDS-staged coalesced writes; blocks 512..543 softmax tables + accum init.
// ---------------------------------------------------------------------------
__global__ __launch_bounds__(256)
void prep_kernel(const float* __restrict__ rp,
                 const float* __restrict__ emb,
                 unsigned char* __restrict__ out8,
                 float* __restrict__ L, float* __restrict__ P,
                 float* __restrict__ ne,
                 float* __restrict__ gsum, unsigned int* __restrict__ gcnt,
                 unsigned int* __restrict__ done) {
    const int b = blockIdx.x;
    const int tid = threadIdx.x;
    if (b < 512) {
        __shared__ __align__(16) unsigned char stage[16 * 1040]; // padded rows
        const int wave = tid >> 6, lane = tid & 63;
        const int g = b;
#pragma unroll
        for (int t = 0; t < 4; t++) {
            int r = g * 16 + wave * 4 + t;
            const float4* row4 = (const float4*)(emb + (size_t)r * H_SZ);
            float4 v0 = row4[lane * 4 + 0], v1 = row4[lane * 4 + 1];
            float4 v2 = row4[lane * 4 + 2], v3 = row4[lane * 4 + 3];
            float ss = v0.x*v0.x + v0.y*v0.y + v0.z*v0.z + v0.w*v0.w
                     + v1.x*v1.x + v1.y*v1.y + v1.z*v1.z + v1.w*v1.w
                     + v2.x*v2.x + v2.y*v2.y + v2.z*v2.z + v2.w*v2.w
                     + v3.x*v3.x + v3.y*v3.y + v3.z*v3.z + v3.w*v3.w;
#pragma unroll
            for (int off = 32; off > 0; off >>= 1) ss += __shfl_down(ss, off, 64);
            ss = __shfl(ss, 0, 64);
            float s = rsqrtf(ss) * 127.0f;
            uint4 c;
            c.x = pack4_i8(v0, s);
            c.y = pack4_i8(v1, s);
            c.z = pack4_i8(v2, s);
            c.w = pack4_i8(v3, s);
            *(uint4*)(stage + (r & 15) * 1040 + lane * 16) = c;
        }
        __syncthreads();
#pragma unroll
        for (int p = 0; p < 4; p++) {
            int d = p * 256 + tid;
            int m = d & 15;
            int c = (d >> 6) * 4 + ((d >> 4) & 3);
            uint4 v = *(const uint4*)(stage + m * 1040 + c * 16);
            *(uint4*)(out8 + (size_t)g * 16384 + (size_t)d * 16) = v;
        }
    } else {
        int i = (b - 512) * 256 + tid;
        if (i == 0) { *gsum = 0.f; *gcnt = 0u; *done = 0u; }
        if (i >= B_SZ) return;
        const float* x = rp + i * E_SZ;
        float v[E_SZ];
        float m = -INFINITY;
#pragma unroll
        for (int k = 0; k < E_SZ; k++) { v[k] = x[k]; m = fmaxf(m, v[k]); }
        float s = 0.f;
#pragma unroll
        for (int k = 0; k < E_SZ; k++) s += expf(v[k] - m);
        float lse = m + logf(s);
        float nent = 0.f;
#pragma unroll
        for (int k = 0; k < E_SZ; k++) {
            float l = v[k] - lse;
            float p = expf(l);
            L[i * E_SZ + k] = l;
            P[i * E_SZ + k] = p;
            nent += p * l;
        }
        ne[i] = nent;
    }
}

// ---------------------------------------------------------------------------
// Main: blocks 0..511 = full 256x256 tiles (64/XCD, R11 engine: 4-slot LDS
// pipeline, fine-grained vmcnt barriers). Blocks 512..575 = the 2 leftover
// tiles per XCD split into 4 quarter-tiles (128x128) each, run with the
// barrier-free direct-global K-loop (latency-bound generation-2 work with
// ~no per-CU DMA contention). Strict j>i rule; per-wave compaction; fused
// finalize via device-scope done counter.
// ---------------------------------------------------------------------------
__global__ __launch_bounds__(1024, 2)
void sim_kl_kernel(const unsigned char* __restrict__ embL,
                   const float* __restrict__ Lm, const float* __restrict__ Pm,
                   const float* __restrict__ ne,
                   float* __restrict__ gsum, unsigned int* __restrict__ gcnt,
                   unsigned int* __restrict__ done, float* __restrict__ out) {
    __shared__ __align__(16) char smem[131072];   // 4-slot A/B pipeline | lists
    __shared__ float redf[16];
    __shared__ unsigned int redc[16];

    const int tid  = threadIdx.x;
    const int lane = tid & 63;
    const int wave = tid >> 6;
    const int quad = lane >> 4;
    const int l16  = lane & 15;

    float fsum = 0.f;
    unsigned int lcnt = 0;

    if (blockIdx.x < 512) {
        // ================= FULL 256x256 TILE (R11 engine) ==================
        const int x = blockIdx.x & 7;
        int s = blockIdx.x >> 3;            // 0..63 (first 64 of 66 per XCD)
        const int phase = s & 15;
        int bjs[4] = { x, x + 8, 23 - x, 31 - x };
        int bi = 0, bj = 0;
#pragma unroll
        for (int t = 0; t < 4; t++) {
            int n = bjs[t] + 1;
            if (s < n) { bj = bjs[t]; bi = s; break; }
            s -= n;
        }
        const int rowI = bi * 256, rowJ = bj * 256;
        const int wrg = wave >> 2;
        const int wcg = wave & 3;

        intx4 acc[4][4];
#pragma unroll
        for (int mi = 0; mi < 4; mi++)
#pragma unroll
            for (int ni = 0; ni < 4; ni++) {
                intx4 z = {0, 0, 0, 0};
                acc[mi][ni] = z;
            }

        const char* srcA = (const char*)embL + (size_t)(bi * 16 + wave) * 16384 + lane * 16;
        const char* srcB = (const char*)embL + (size_t)(bj * 16 + wave) * 16384 + lane * 16;
        const int gW = wave * 1024;

#pragma unroll
        for (int p = 0; p < 3; p++) {
            const int ko = ((p + phase) & 15) * 1024;
            gload16(srcA + ko, smem + p * 16384 + gW);
            gload16(srcB + ko, smem + 65536 + p * 16384 + gW);
        }

        const int aoff = wrg * 4096 + lane * 16;
        const int boff = 65536 + wcg * 4096 + lane * 16;

#pragma unroll
        for (int kt = 0; kt < 16; kt++) {
            if (kt < 14)
                asm volatile("s_waitcnt vmcnt(4)\ns_barrier" ::: "memory");
            else if (kt == 14)
                asm volatile("s_waitcnt vmcnt(2)\ns_barrier" ::: "memory");
            else
                asm volatile("s_waitcnt vmcnt(0)\ns_barrier" ::: "memory");

            const int slot = kt & 3;
            intx4 af[4], bf[4];
#pragma unroll
            for (int mi = 0; mi < 4; mi++)
                af[mi] = *(const intx4*)(smem + slot * 16384 + aoff + mi * 1024);
#pragma unroll
            for (int ni = 0; ni < 4; ni++)
                bf[ni] = *(const intx4*)(smem + slot * 16384 + boff + ni * 1024);
#pragma unroll
            for (int mi = 0; mi < 4; mi++)
#pragma unroll
                for (int ni = 0; ni < 4; ni++)
                    acc[mi][ni] = __builtin_amdgcn_mfma_i32_16x16x64_i8(
                        af[mi], bf[ni], acc[mi][ni], 0, 0, 0);

            if (kt + 3 < 16) {
                const int ko = ((kt + 3 + phase) & 15) * 1024;
                const int ps = (kt + 3) & 3;
                gload16(srcA + ko, smem + ps * 16384 + gW);
                gload16(srcB + ko, smem + 65536 + ps * 16384 + gW);
            }
        }

        __syncthreads();             // drain; overlay lists on smem
        unsigned short* wl = (unsigned short*)smem + wave * 2048;
        int base = 0;
#pragma unroll
        for (int mi = 0; mi < 4; mi++) {
#pragma unroll
            for (int ni = 0; ni < 4; ni++) {
#pragma unroll
                for (int r = 0; r < 4; r++) {
                    int il = wrg * 64 + mi * 16 + quad * 4 + r;
                    int jl = wcg * 64 + ni * 16 + l16;
                    bool msk = (acc[mi][ni][r] > SIM_THR_I) && (rowJ + jl > rowI + il);
                    unsigned long long bal = __ballot(msk);
                    if (msk) {
                        int pos = base + __popcll(bal & ((1ull << lane) - 1ull));
                        if (pos < 2048) wl[pos] = (unsigned short)((il << 8) | jl);
                    }
                    base += __popcll(bal);
                }
            }
        }
        if (base > 2048) base = 2048;

        for (int t = lane; t < base; t += 64) {
            int e = wl[t];
            int i = rowI + (e >> 8), j = rowJ + (e & 255);
            const float4* Li4 = (const float4*)(Lm + i * E_SZ);
            const float4* Pj4 = (const float4*)(Pm + j * E_SZ);
            const float4* Lj4 = (const float4*)(Lm + j * E_SZ);
            const float4* Pi4 = (const float4*)(Pm + i * E_SZ);
            float d = 0.f, d2 = 0.f;
#pragma unroll
            for (int q = 0; q < 4; q++) {
                float4 a = Li4[q], bb = Pj4[q];
                d += a.x * bb.x + a.y * bb.y + a.z * bb.z + a.w * bb.w;
                float4 a2 = Lj4[q], b2 = Pi4[q];
                d2 += a2.x * b2.x + a2.y * b2.y + a2.z * b2.z + a2.w * b2.w;
            }
            fsum += (ne[j] - d) + (ne[i] - d2);
            lcnt += 2;
        }
    } else {
        // ============ QUARTER TILE 128x128 (direct-global engine) ==========
        const int q0 = blockIdx.x - 512;
        const int x  = q0 & 7;
        const int e  = q0 >> 3;            // 0..7 per XCD
        const int bj = 31 - x;
        const int bi = 30 - x + (e >> 2);  // entries 64,65 of the XCD list
        const int h  = (e >> 1) & 1;       // row half
        const int c  = e & 1;              // col half
        const int rowI = bi * 256, rowJ = bj * 256;
        const int rI0 = rowI + h * 128, rJ0 = rowJ + c * 128;

        intx4 acc[2][2];
#pragma unroll
        for (int mi = 0; mi < 2; mi++)
#pragma unroll
            for (int ni = 0; ni < 2; ni++) {
                intx4 z = {0, 0, 0, 0};
                acc[mi][ni] = z;
            }

        const bool skip = (rJ0 + 127 <= rI0);   // entirely i>=j: no pairs
        if (!skip) {
            const int wrg = wave >> 2;          // 0..3: 32-row slab
            const int wcg = wave & 3;           // 0..3: 32-col slab
            const char* pA = (const char*)embL
                + (size_t)(bi * 16 + h * 8 + wrg * 2) * 16384 + lane * 16;
            const char* pB = (const char*)embL
                + (size_t)(bj * 16 + c * 8 + wcg * 2) * 16384 + lane * 16;

            intx4 fa[3][2], fb[3][2];
#pragma unroll
            for (int p = 0; p < 3; p++)
#pragma unroll
                for (int mi = 0; mi < 2; mi++) {
                    fa[p][mi] = *(const intx4*)(pA + mi * 16384 + p * 1024);
                    fb[p][mi] = *(const intx4*)(pB + mi * 16384 + p * 1024);
                }
#pragma unroll
            for (int kt = 0; kt < 16; kt++) {
                const int buf = kt % 3;
#pragma unroll
                for (int mi = 0; mi < 2; mi++)
#pragma unroll
                    for (int ni = 0; ni < 2; ni++)
                        acc[mi][ni] = __builtin_amdgcn_mfma_i32_16x16x64_i8(
                            fa[buf][mi], fb[buf][ni], acc[mi][ni], 0, 0, 0);
                if (kt + 3 < 16) {
                    const int ko = (kt + 3) * 1024;
#pragma unroll
                    for (int mi = 0; mi < 2; mi++) {
                        fa[buf][mi] = *(const intx4*)(pA + mi * 16384 + ko);
                        fb[buf][mi] = *(const intx4*)(pB + mi * 16384 + ko);
                    }
                }
            }

            unsigned short* wl = (unsigned short*)smem + wave * 2048;
            int base = 0;
            const int wrl = h * 128 + wrg * 32;   // tile-local row base
            const int wcl = c * 128 + wcg * 32;   // tile-local col base
#pragma unroll
            for (int mi = 0; mi < 2; mi++) {
#pragma unroll
                for (int ni = 0; ni < 2; ni++) {
#pragma unroll
                    for (int r = 0; r < 4; r++) {
                        int il = wrl + mi * 16 + quad * 4 + r;
                        int jl = wcl + ni * 16 + l16;
                        bool msk = (acc[mi][ni][r] > SIM_THR_I) && (rowJ + jl > rowI + il);
                        unsigned long long bal = __ballot(msk);
                        if (msk) {
                            int pos = base + __popcll(bal & ((1ull << lane) - 1ull));
                            if (pos < 2048) wl[pos] = (unsigned short)((il << 8) | jl);
                        }
                        base += __popcll(bal);
                    }
                }
            }
            if (base > 2048) base = 2048;

            for (int t = lane; t < base; t += 64) {
                int eidx = wl[t];
                int i = rowI + (eidx >> 8), j = rowJ + (eidx & 255);
                const float4* Li4 = (const float4*)(Lm + i * E_SZ);
                const float4* Pj4 = (const float4*)(Pm + j * E_SZ);
                const float4* Lj4 = (const float4*)(Lm + j * E_SZ);
                const float4* Pi4 = (const float4*)(Pm + i * E_SZ);
                float d = 0.f, d2 = 0.f;
#pragma unroll
                for (int q = 0; q < 4; q++) {
                    float4 a = Li4[q], bb = Pj4[q];
                    d += a.x * bb.x + a.y * bb.y + a.z * bb.z + a.w * bb.w;
                    float4 a2 = Lj4[q], b2 = Pi4[q];
                    d2 += a2.x * b2.x + a2.y * b2.y + a2.z * b2.z + a2.w * b2.w;
                }
                fsum += (ne[j] - d) + (ne[i] - d2);
                lcnt += 2;
            }
        }
    }

    // ======================= common reduction + finalize ====================
#pragma unroll
    for (int off = 32; off > 0; off >>= 1) {
        fsum += __shfl_down(fsum, off, 64);
        lcnt += __shfl_down(lcnt, off, 64);
    }
    if (lane == 0) { redf[wave] = fsum; redc[wave] = lcnt; }
    __syncthreads();
    if (tid == 0) {
        float sv = 0.f;
        unsigned int c = 0u;
#pragma unroll
        for (int w = 0; w < 16; w++) { sv += redf[w]; c += redc[w]; }
        if (c > 0u) {
            atomicAdd(gsum, sv);
            atomicAdd(gcnt, c);
        }
        __threadfence();
        unsigned int old = atomicAdd(done, 1u);
        if (old == gridDim.x - 1) {
            float S = atomicAdd(gsum, 0.0f);
            unsigned int C = atomicAdd(gcnt, 0u);
            out[0] = (C > 0u) ? (S / (float)C) : 0.f;   // WEIGHT = 1.0
        }
    }
}

// ---------------------------------------------------------------------------
extern "C" void kernel_launch(void* const* d_in, const int* in_sizes, int n_in,
                              void* d_out, int out_size, void* d_ws, size_t ws_size,
                              hipStream_t stream) {
    const float* rp  = (const float*)d_in[0];
    const float* emb = (const float*)d_in[1];
    float* out = (float*)d_out;

    char* ws = (char*)d_ws;
    float*         gsum = (float*)(ws + 0);
    unsigned int*  gcnt = (unsigned int*)(ws + 4);
    unsigned int*  done = (unsigned int*)(ws + 8);
    float*         ne   = (float*)(ws + OFF_NE);
    float*         Lm   = (float*)(ws + OFF_L);
    float*         Pm   = (float*)(ws + OFF_P);
    unsigned char* embL = (unsigned char*)(ws + OFF_EMB);

    prep_kernel<<<512 + 32, 256, 0, stream>>>(rp, emb, embL, Lm, Pm, ne, gsum, gcnt, done);
    sim_kl_kernel<<<576, 1024, 0, stream>>>(embL, Lm, Pm, ne, gsum, gcnt, done, out);
}

// Round 14
// 143.774 us; speedup vs baseline: 1.2009x; 1.0026x over previous
//
#include <hip/hip_runtime.h>
#include <hip/hip_bf16.h>
#include <math.h>

// Problem constants: B=8192, E=16, H=1024
#define B_SZ 8192
#define H_SZ 1024
#define E_SZ 16
#define SIM_THR_I 12903   // 0.8 * 127 * 127 = 12903.2 -> D > 12903
typedef float floatx4 __attribute__((ext_vector_type(4)));
typedef int   intx4   __attribute__((ext_vector_type(4)));

// ---------------- workspace layout ----------------
// 0: float gsum | 4: uint gcnt | 8: uint done
#define OFF_NE   4096
#define OFF_L    65536
#define OFF_P    (65536 + 524288)
#define OFF_EMB  2097152   // i8 emb, MFMA-native layout: 8 MB

// MFMA-native i8 layout (for mfma_i32_16x16x64_i8, lane q*16+m holds rows m,
// k in [q*16, q*16+16) contiguous):
// addr(r,k) = (r>>4)*16384 + (k>>6)*1024 + ((k>>4)&3)*256 + (r&15)*16 + (k&15)

__device__ __forceinline__ void gload16(const void* g, void* l) {
    __builtin_amdgcn_global_load_lds(
        (const __attribute__((address_space(1))) void*)g,
        (__attribute__((address_space(3))) void*)l, 16, 0, 0);
}

__device__ __forceinline__ unsigned int pack4_i8(float4 v, float s) {
    int a = (int)rintf(v.x * s), b = (int)rintf(v.y * s);
    int c = (int)rintf(v.z * s), d = (int)rintf(v.w * s);
    return (a & 255) | ((b & 255) << 8) | ((c & 255) << 16) | ((d & 255) << 24);
}

// ---------------------------------------------------------------------------
// Prep: blocks 0..511 normalize 16 rows each -> i8 MFMA-native layout with
// LDS-staged coalesced writes; blocks 512..543 softmax tables + accum init.
// ---------------------------------------------------------------------------
__global__ __launch_bounds__(256)
void prep_kernel(const float* __restrict__ rp,
                 const float* __restrict__ emb,
                 unsigned char* __restrict__ out8,
                 float* __restrict__ L, float* __restrict__ P,
                 float* __restrict__ ne,
                 float* __restrict__ gsum, unsigned int* __restrict__ gcnt,
                 unsigned int* __restrict__ done) {
    const int b = blockIdx.x;
    const int tid = threadIdx.x;
    if (b < 512) {
        __shared__ __align__(16) unsigned char stage[16 * 1040]; // padded rows
        const int wave = tid >> 6, lane = tid & 63;
        const int g = b;
#pragma unroll
        for (int t = 0; t < 4; t++) {
            int r = g * 16 + wave * 4 + t;
            const float4* row4 = (const float4*)(emb + (size_t)r * H_SZ);
            float4 v0 = row4[lane * 4 + 0], v1 = row4[lane * 4 + 1];
            float4 v2 = row4[lane * 4 + 2], v3 = row4[lane * 4 + 3];
            float ss = v0.x*v0.x + v0.y*v0.y + v0.z*v0.z + v0.w*v0.w
                     + v1.x*v1.x + v1.y*v1.y + v1.z*v1.z + v1.w*v1.w
                     + v2.x*v2.x + v2.y*v2.y + v2.z*v2.z + v2.w*v2.w
                     + v3.x*v3.x + v3.y*v3.y + v3.z*v3.z + v3.w*v3.w;
#pragma unroll
            for (int off = 32; off > 0; off >>= 1) ss += __shfl_down(ss, off, 64);
            ss = __shfl(ss, 0, 64);
            float s = rsqrtf(ss) * 127.0f;
            uint4 c;
            c.x = pack4_i8(v0, s);
            c.y = pack4_i8(v1, s);
            c.z = pack4_i8(v2, s);
            c.w = pack4_i8(v3, s);
            *(uint4*)(stage + (r & 15) * 1040 + lane * 16) = c;
        }
        __syncthreads();
#pragma unroll
        for (int p = 0; p < 4; p++) {
            int d = p * 256 + tid;
            int m = d & 15;
            int c = (d >> 6) * 4 + ((d >> 4) & 3);
            uint4 v = *(const uint4*)(stage + m * 1040 + c * 16);
            *(uint4*)(out8 + (size_t)g * 16384 + (size_t)d * 16) = v;
        }
    } else {
        int i = (b - 512) * 256 + tid;
        if (i == 0) { *gsum = 0.f; *gcnt = 0u; *done = 0u; }
        if (i >= B_SZ) return;
        const float* x = rp + i * E_SZ;
        float v[E_SZ];
        float m = -INFINITY;
#pragma unroll
        for (int k = 0; k < E_SZ; k++) { v[k] = x[k]; m = fmaxf(m, v[k]); }
        float s = 0.f;
#pragma unroll
        for (int k = 0; k < E_SZ; k++) s += expf(v[k] - m);
        float lse = m + logf(s);
        float nent = 0.f;
#pragma unroll
        for (int k = 0; k < E_SZ; k++) {
            float l = v[k] - lse;
            float p = expf(l);
            L[i * E_SZ + k] = l;
            P[i * E_SZ + k] = p;
            nent += p * l;
        }
        ne[i] = nent;
    }
}

// ---------------------------------------------------------------------------
// Main: blocks 0..511 = full 256x256 tiles, 2-slot LDS double-buffer with
// drain-barrier (R10 engine) at 64 KB LDS -> 2 blocks/CU -> ALL 512 tiles
// co-resident in ONE generation. Blocks 512..575 = the 2 leftover tiles per
// XCD split into 4 quarter-tiles (128x128), barrier-free direct-global
// engine (latency-bound backfill generation). Strict j>i rule; per-wave
// compaction; fused finalize via device-scope done counter.
//
// LDS budget: 2 slots x 32 KB (A 16 KB + B 16 KB) = 64 KB, overlaid by the
// 16 x 2048-entry u16 compaction lists (exactly 64 KB) after the K-loop.
// ---------------------------------------------------------------------------
__global__ __launch_bounds__(1024, 2)
void sim_kl_kernel(const unsigned char* __restrict__ embL,
                   const float* __restrict__ Lm, const float* __restrict__ Pm,
                   const float* __restrict__ ne,
                   float* __restrict__ gsum, unsigned int* __restrict__ gcnt,
                   unsigned int* __restrict__ done, float* __restrict__ out) {
    __shared__ __align__(16) char smem[2][32768];   // slot: A@0, B@16384
    __shared__ float redf[16];
    __shared__ unsigned int redc[16];

    const int tid  = threadIdx.x;
    const int lane = tid & 63;
    const int wave = tid >> 6;
    const int quad = lane >> 4;
    const int l16  = lane & 15;

    float fsum = 0.f;
    unsigned int lcnt = 0;

    if (blockIdx.x < 512) {
        // ============ FULL 256x256 TILE (2-slot drain engine, R10) =========
        const int x = blockIdx.x & 7;
        int s = blockIdx.x >> 3;            // 0..63 (first 64 of 66 per XCD)
        const int phase = s & 15;
        int bjs[4] = { x, x + 8, 23 - x, 31 - x };
        int bi = 0, bj = 0;
#pragma unroll
        for (int t = 0; t < 4; t++) {
            int n = bjs[t] + 1;
            if (s < n) { bj = bjs[t]; bi = s; break; }
            s -= n;
        }
        const int rowI = bi * 256, rowJ = bj * 256;
        const int wrg = wave >> 2;
        const int wcg = wave & 3;

        intx4 acc[4][4];
#pragma unroll
        for (int mi = 0; mi < 4; mi++)
#pragma unroll
            for (int ni = 0; ni < 4; ni++) {
                intx4 z = {0, 0, 0, 0};
                acc[mi][ni] = z;
            }

        const char* srcA = (const char*)embL + (size_t)(bi * 16 + wave) * 16384 + lane * 16;
        const char* srcB = (const char*)embL + (size_t)(bj * 16 + wave) * 16384 + lane * 16;
        const int gW = wave * 1024;

        {   // prologue: stage round 'phase' into slot 0
            const int ko = phase * 1024;
            gload16(srcA + ko, smem[0] + gW);
            gload16(srcB + ko, smem[0] + 16384 + gW);
        }

        const int aoff = wrg * 4096 + lane * 16;           // + mi*1024
        const int boff = 16384 + wcg * 4096 + lane * 16;   // + ni*1024

        for (int kt = 0; kt < 16; kt++) {
            const int b = kt & 1;
            __syncthreads();                 // vmcnt drain + barrier: slot b ready
            if (kt + 1 < 16) {               // issue next round; overlaps MFMAs
                const int ko = (((kt + 1) + phase) & 15) * 1024;
                gload16(srcA + ko, smem[b ^ 1] + gW);
                gload16(srcB + ko, smem[b ^ 1] + 16384 + gW);
            }

            intx4 af[4], bf[4];
#pragma unroll
            for (int mi = 0; mi < 4; mi++)
                af[mi] = *(const intx4*)(smem[b] + aoff + mi * 1024);
#pragma unroll
            for (int ni = 0; ni < 4; ni++)
                bf[ni] = *(const intx4*)(smem[b] + boff + ni * 1024);
#pragma unroll
            for (int mi = 0; mi < 4; mi++)
#pragma unroll
                for (int ni = 0; ni < 4; ni++)
                    acc[mi][ni] = __builtin_amdgcn_mfma_i32_16x16x64_i8(
                        af[mi], bf[ni], acc[mi][ni], 0, 0, 0);
        }

        __syncthreads();             // drain; overlay lists on smem
        unsigned short* wl = (unsigned short*)smem + wave * 2048;
        int base = 0;
        // C/D layout (16x16 shape): col = lane&15, row = quad*4 + reg
#pragma unroll
        for (int mi = 0; mi < 4; mi++) {
#pragma unroll
            for (int ni = 0; ni < 4; ni++) {
#pragma unroll
                for (int r = 0; r < 4; r++) {
                    int il = wrg * 64 + mi * 16 + quad * 4 + r;
                    int jl = wcg * 64 + ni * 16 + l16;
                    bool msk = (acc[mi][ni][r] > SIM_THR_I) && (rowJ + jl > rowI + il);
                    unsigned long long bal = __ballot(msk);
                    if (msk) {
                        int pos = base + __popcll(bal & ((1ull << lane) - 1ull));
                        if (pos < 2048) wl[pos] = (unsigned short)((il << 8) | jl);
                    }
                    base += __popcll(bal);
                }
            }
        }
        if (base > 2048) base = 2048;

        for (int t = lane; t < base; t += 64) {
            int e = wl[t];
            int i = rowI + (e >> 8), j = rowJ + (e & 255);
            const float4* Li4 = (const float4*)(Lm + i * E_SZ);
            const float4* Pj4 = (const float4*)(Pm + j * E_SZ);
            const float4* Lj4 = (const float4*)(Lm + j * E_SZ);
            const float4* Pi4 = (const float4*)(Pm + i * E_SZ);
            float d = 0.f, d2 = 0.f;
#pragma unroll
            for (int q = 0; q < 4; q++) {
                float4 a = Li4[q], bb = Pj4[q];
                d += a.x * bb.x + a.y * bb.y + a.z * bb.z + a.w * bb.w;
                float4 a2 = Lj4[q], b2 = Pi4[q];
                d2 += a2.x * b2.x + a2.y * b2.y + a2.z * b2.z + a2.w * b2.w;
            }
            fsum += (ne[j] - d) + (ne[i] - d2);
            lcnt += 2;
        }
    } else {
        // ============ QUARTER TILE 128x128 (direct-global engine) ==========
        const int q0 = blockIdx.x - 512;
        const int x  = q0 & 7;
        const int e  = q0 >> 3;            // 0..7 per XCD
        const int bj = 31 - x;
        const int bi = 30 - x + (e >> 2);  // entries 64,65 of the XCD list
        const int h  = (e >> 1) & 1;       // row half
        const int c  = e & 1;              // col half
        const int rowI = bi * 256, rowJ = bj * 256;
        const int rI0 = rowI + h * 128, rJ0 = rowJ + c * 128;

        intx4 acc[2][2];
#pragma unroll
        for (int mi = 0; mi < 2; mi++)
#pragma unroll
            for (int ni = 0; ni < 2; ni++) {
                intx4 z = {0, 0, 0, 0};
                acc[mi][ni] = z;
            }

        const bool skip = (rJ0 + 127 <= rI0);   // entirely i>=j: no pairs
        if (!skip) {
            const int wrg = wave >> 2;          // 0..3: 32-row slab
            const int wcg = wave & 3;           // 0..3: 32-col slab
            const char* pA = (const char*)embL
                + (size_t)(bi * 16 + h * 8 + wrg * 2) * 16384 + lane * 16;
            const char* pB = (const char*)embL
                + (size_t)(bj * 16 + c * 8 + wcg * 2) * 16384 + lane * 16;

            intx4 fa[3][2], fb[3][2];
#pragma unroll
            for (int p = 0; p < 3; p++)
#pragma unroll
                for (int mi = 0; mi < 2; mi++) {
                    fa[p][mi] = *(const intx4*)(pA + mi * 16384 + p * 1024);
                    fb[p][mi] = *(const intx4*)(pB + mi * 16384 + p * 1024);
                }
#pragma unroll
            for (int kt = 0; kt < 16; kt++) {
                const int buf = kt % 3;
#pragma unroll
                for (int mi = 0; mi < 2; mi++)
#pragma unroll
                    for (int ni = 0; ni < 2; ni++)
                        acc[mi][ni] = __builtin_amdgcn_mfma_i32_16x16x64_i8(
                            fa[buf][mi], fb[buf][ni], acc[mi][ni], 0, 0, 0);
                if (kt + 3 < 16) {
                    const int ko = (kt + 3) * 1024;
#pragma unroll
                    for (int mi = 0; mi < 2; mi++) {
                        fa[buf][mi] = *(const intx4*)(pA + mi * 16384 + ko);
                        fb[buf][mi] = *(const intx4*)(pB + mi * 16384 + ko);
                    }
                }
            }

            unsigned short* wl = (unsigned short*)smem + wave * 2048;
            int base = 0;
            const int wrl = h * 128 + wrg * 32;   // tile-local row base
            const int wcl = c * 128 + wcg * 32;   // tile-local col base
#pragma unroll
            for (int mi = 0; mi < 2; mi++) {
#pragma unroll
                for (int ni = 0; ni < 2; ni++) {
#pragma unroll
                    for (int r = 0; r < 4; r++) {
                        int il = wrl + mi * 16 + quad * 4 + r;
                        int jl = wcl + ni * 16 + l16;
                        bool msk = (acc[mi][ni][r] > SIM_THR_I) && (rowJ + jl > rowI + il);
                        unsigned long long bal = __ballot(msk);
                        if (msk) {
                            int pos = base + __popcll(bal & ((1ull << lane) - 1ull));
                            if (pos < 2048) wl[pos] = (unsigned short)((il << 8) | jl);
                        }
                        base += __popcll(bal);
                    }
                }
            }
            if (base > 2048) base = 2048;

            for (int t = lane; t < base; t += 64) {
                int eidx = wl[t];
                int i = rowI + (eidx >> 8), j = rowJ + (eidx & 255);
                const float4* Li4 = (const float4*)(Lm + i * E_SZ);
                const float4* Pj4 = (const float4*)(Pm + j * E_SZ);
                const float4* Lj4 = (const float4*)(Lm + j * E_SZ);
                const float4* Pi4 = (const float4*)(Pm + i * E_SZ);
                float d = 0.f, d2 = 0.f;
#pragma unroll
                for (int q = 0; q < 4; q++) {
                    float4 a = Li4[q], bb = Pj4[q];
                    d += a.x * bb.x + a.y * bb.y + a.z * bb.z + a.w * bb.w;
                    float4 a2 = Lj4[q], b2 = Pi4[q];
                    d2 += a2.x * b2.x + a2.y * b2.y + a2.z * b2.z + a2.w * b2.w;
                }
                fsum += (ne[j] - d) + (ne[i] - d2);
                lcnt += 2;
            }
        }
    }

    // ======================= common reduction + finalize ====================
#pragma unroll
    for (int off = 32; off > 0; off >>= 1) {
        fsum += __shfl_down(fsum, off, 64);
        lcnt += __shfl_down(lcnt, off, 64);
    }
    if (lane == 0) { redf[wave] = fsum; redc[wave] = lcnt; }
    __syncthreads();
    if (tid == 0) {
        float sv = 0.f;
        unsigned int c = 0u;
#pragma unroll
        for (int w = 0; w < 16; w++) { sv += redf[w]; c += redc[w]; }
        if (c > 0u) {
            atomicAdd(gsum, sv);
            atomicAdd(gcnt, c);
        }
        __threadfence();
        unsigned int old = atomicAdd(done, 1u);
        if (old == gridDim.x - 1) {
            float S = atomicAdd(gsum, 0.0f);
            unsigned int C = atomicAdd(gcnt, 0u);
            out[0] = (C > 0u) ? (S / (float)C) : 0.f;   // WEIGHT = 1.0
        }
    }
}

// ---------------------------------------------------------------------------
extern "C" void kernel_launch(void* const* d_in, const int* in_sizes, int n_in,
                              void* d_out, int out_size, void* d_ws, size_t ws_size,
                              hipStream_t stream) {
    const float* rp  = (const float*)d_in[0];
    const float* emb = (const float*)d_in[1];
    float* out = (float*)d_out;

    char* ws = (char*)d_ws;
    float*         gsum = (float*)(ws + 0);
    unsigned int*  gcnt = (unsigned int*)(ws + 4);
    unsigned int*  done = (unsigned int*)(ws + 8);
    float*         ne   = (float*)(ws + OFF_NE);
    float*         Lm   = (float*)(ws + OFF_L);
    float*         Pm   = (float*)(ws + OFF_P);
    unsigned char* embL = (unsigned char*)(ws + OFF_EMB);

    prep_kernel<<<512 + 32, 256, 0, stream>>>(rp, emb, embL, Lm, Pm, ne, gsum, gcnt, done);
    sim_kl_kernel<<<576, 1024, 0, stream>>>(embL, Lm, Pm, ne, gsum, gcnt, done, out);
}